// Round 1
// baseline (299.937 us; speedup 1.0000x reference)
//
#include <hip/hip_runtime.h>
#include <climits>

#define HH 1024
#define WW 1024
#define DD 128
#define NPIX (HH * WW)

// ws layout (as float*/int*):
//   ints  [0]=rmin [1]=rmax [2]=cmin [3]=cmax [4]=count
//   float [64 .. 64+512)   M (4x128 row-major: M[r*128+j])
//   float [576 .. 704)     c (128)
//   float [1024 .. )       partials B*128

// ---------------- K0: init stats + precompute M = W1@W2, c = b1@W2 + b2 ----
__global__ void k0_prep(const float* __restrict__ W1, const float* __restrict__ b1,
                        const float* __restrict__ W2, const float* __restrict__ b2,
                        float* __restrict__ wsf, int* __restrict__ wsi) {
    int j = threadIdx.x;  // 128 threads
    if (j == 0) {
        wsi[0] = INT_MAX;  // rmin
        wsi[1] = -1;       // rmax
        wsi[2] = INT_MAX;  // cmin
        wsi[3] = -1;       // cmax
        wsi[4] = 0;        // count
    }
    float m0 = 0.f, m1 = 0.f, m2 = 0.f, m3 = 0.f, cc = 0.f;
    for (int d = 0; d < DD; ++d) {
        float w2 = W2[d * DD + j];
        m0 = fmaf(W1[0 * DD + d], w2, m0);
        m1 = fmaf(W1[1 * DD + d], w2, m1);
        m2 = fmaf(W1[2 * DD + d], w2, m2);
        m3 = fmaf(W1[3 * DD + d], w2, m3);
        cc = fmaf(b1[d], w2, cc);
    }
    wsf[64 + 0 * DD + j] = m0;
    wsf[64 + 1 * DD + j] = m1;
    wsf[64 + 2 * DD + j] = m2;
    wsf[64 + 3 * DD + j] = m3;
    wsf[576 + j] = cc + b2[j];
}

// ---------------- K1: masked min/max of row/col + count ---------------------
__global__ __launch_bounds__(256) void k1_stats(const float* __restrict__ x0,
                                                int* __restrict__ wsi) {
    int tid = blockIdx.x * blockDim.x + threadIdx.x;
    int stride = gridDim.x * blockDim.x;
    int rmin = INT_MAX, rmax = -1, cmin = INT_MAX, cmax = -1, cnt = 0;
    for (int i = tid; i < NPIX; i += stride) {
        float v = x0[i];
        if (v != 0.0f) {
            int r = i >> 10;
            int c = i & (WW - 1);
            rmin = min(rmin, r);
            rmax = max(rmax, r);
            cmin = min(cmin, c);
            cmax = max(cmax, c);
            cnt++;
        }
    }
    // wave-level reduce (64 lanes)
    for (int off = 32; off >= 1; off >>= 1) {
        rmin = min(rmin, __shfl_down(rmin, off, 64));
        rmax = max(rmax, __shfl_down(rmax, off, 64));
        cmin = min(cmin, __shfl_down(cmin, off, 64));
        cmax = max(cmax, __shfl_down(cmax, off, 64));
        cnt += __shfl_down(cnt, off, 64);
    }
    // block-level reduce across 4 waves via LDS
    __shared__ int s[4][5];
    int wave = threadIdx.x >> 6;
    int lane = threadIdx.x & 63;
    if (lane == 0) {
        s[wave][0] = rmin; s[wave][1] = rmax;
        s[wave][2] = cmin; s[wave][3] = cmax; s[wave][4] = cnt;
    }
    __syncthreads();
    if (threadIdx.x == 0) {
        int a0 = s[0][0], a1 = s[0][1], a2 = s[0][2], a3 = s[0][3], a4 = s[0][4];
        for (int w = 1; w < 4; ++w) {
            a0 = min(a0, s[w][0]); a1 = max(a1, s[w][1]);
            a2 = min(a2, s[w][2]); a3 = max(a3, s[w][3]); a4 += s[w][4];
        }
        atomicMin(&wsi[0], a0);
        atomicMax(&wsi[1], a1);
        atomicMin(&wsi[2], a2);
        atomicMax(&wsi[3], a3);
        atomicAdd(&wsi[4], a4);
    }
}

// ---------------- K2: main accumulate ---------------------------------------
#define TILE 256
__global__ __launch_bounds__(256) void k2_main(const float* __restrict__ x0,
                                               const float* __restrict__ x1,
                                               const float* __restrict__ wsf,
                                               const int* __restrict__ wsi,
                                               float* __restrict__ partials,
                                               int C) {
    __shared__ float s0[TILE];
    __shared__ float s1[TILE];
    __shared__ float red[256];

    int tid = threadIdx.x;
    int j = tid & 127;   // feature
    int g = tid >> 7;    // pixel group 0/1

    int rmin = wsi[0], rmax = wsi[1], cmin = wsi[2], cmax = wsi[3];
    float rs = 1.0f / (float)(rmax - rmin);
    float cs = 1.0f / (float)(cmax - cmin);

    float M0 = wsf[64 + 0 * DD + j];
    float M1 = wsf[64 + 1 * DD + j];
    float M2 = wsf[64 + 2 * DD + j];
    float M3 = wsf[64 + 3 * DD + j];
    float cj = wsf[576 + j];

    float a0 = M0 * rs;
    float a1 = M1 * cs;
    // fold the -min shifts into the constant
    float cp = cj - (float)rmin * a0 - (float)cmin * a1;

    float acc = 0.0f;

    int start = blockIdx.x * C;
    int end = start + C;
    if (end > NPIX) end = NPIX;

    for (int tb = start; tb < end; tb += TILE) {
        int li = tb + tid;
        // out-of-range -> 0 -> masked out by (v0 != 0)
        s0[tid] = (li < end) ? x0[li] : 0.0f;
        s1[tid] = (li < end) ? x1[li] : 0.0f;
        __syncthreads();

        int pbase = g * 128;
        #pragma unroll 8
        for (int p = 0; p < 128; ++p) {
            int lp = pbase + p;
            float v0 = s0[lp];   // uniform per wave -> LDS broadcast
            float v1 = s1[lp];
            int idx = tb + lp;
            float row = (float)(idx >> 10);
            float col = (float)(idx & (WW - 1));
            float dot = fmaf(row, a0, fmaf(col, a1, fmaf(v0, M2, fmaf(v1, M3, cp))));
            float r = fmaxf(dot, 0.0f);
            acc += (v0 != 0.0f) ? r : 0.0f;
        }
        __syncthreads();
    }

    red[tid] = acc;
    __syncthreads();
    if (tid < 128) {
        partials[blockIdx.x * 128 + tid] = red[tid] + red[tid + 128];
    }
}

// ---------------- K3: reduce partials + final 128x128 matvec ----------------
__global__ void k3_final(const float* __restrict__ partials, const int* __restrict__ wsi,
                         const float* __restrict__ W3, const float* __restrict__ b3,
                         float* __restrict__ out, int B) {
    __shared__ float m[128];
    int j = threadIdx.x;  // 128 threads
    float S = 0.0f;
    for (int b = 0; b < B; ++b) S += partials[b * 128 + j];
    float cnt = (float)wsi[4];
    m[j] = S / cnt;
    __syncthreads();
    float acc = b3[j];
    for (int d = 0; d < DD; ++d) acc = fmaf(m[d], W3[d * DD + j], acc);
    out[j] = acc;
}

extern "C" void kernel_launch(void* const* d_in, const int* in_sizes, int n_in,
                              void* d_out, int out_size, void* d_ws, size_t ws_size,
                              hipStream_t stream) {
    const float* x  = (const float*)d_in[0];
    const float* x0 = x;
    const float* x1 = x + NPIX;
    const float* W1 = (const float*)d_in[1];
    const float* b1 = (const float*)d_in[2];
    const float* W2 = (const float*)d_in[3];
    const float* b2 = (const float*)d_in[4];
    const float* W3 = (const float*)d_in[5];
    const float* b3 = (const float*)d_in[6];
    float* out = (float*)d_out;

    float* wsf = (float*)d_ws;
    int*   wsi = (int*)d_ws;

    // choose B (number of K2 blocks) to fit workspace
    size_t avail = ws_size / 4;
    int B = 1024;
    if (avail < (size_t)(1024 + B * 128)) {
        B = (int)((avail > 1024 ? avail - 1024 : 128) / 128);
        if (B < 1) B = 1;
    }
    int C = (NPIX + B - 1) / B;
    float* partials = wsf + 1024;

    hipLaunchKernelGGL(k0_prep, dim3(1), dim3(128), 0, stream, W1, b1, W2, b2, wsf, wsi);
    hipLaunchKernelGGL(k1_stats, dim3(512), dim3(256), 0, stream, x0, wsi);
    hipLaunchKernelGGL(k2_main, dim3(B), dim3(256), 0, stream, x0, x1, wsf, wsi, partials, C);
    hipLaunchKernelGGL(k3_final, dim3(1), dim3(128), 0, stream, partials, wsi, W3, b3, out, B);
}

// Round 2
// 71.130 us; speedup vs baseline: 4.2167x; 4.2167x over previous
//
#include <hip/hip_runtime.h>
#include <climits>

#define HH 1024
#define WW 1024
#define DD 128
#define NPIX (HH * WW)

// ws layout (as float*/int*):
//   ints  [0]=rmin [1]=rmax [2]=cmin [3]=cmax [4]=count
//   float [64 .. 64+512)   M (4x128 row-major: M[r*128+j])
//   float [576 .. 704)     c (128)
//   float [704 .. 832)     m (mean hidden vector, 128)
//   float [1024 .. )       partials B*128

// ---------------- K0: init stats + precompute M = W1@W2, c = b1@W2 + b2 ----
__global__ void k0_prep(const float* __restrict__ W1, const float* __restrict__ b1,
                        const float* __restrict__ W2, const float* __restrict__ b2,
                        float* __restrict__ wsf, int* __restrict__ wsi) {
    int j = threadIdx.x;  // 128 threads
    if (j == 0) {
        wsi[0] = INT_MAX;  // rmin
        wsi[1] = -1;       // rmax
        wsi[2] = INT_MAX;  // cmin
        wsi[3] = -1;       // cmax
        wsi[4] = 0;        // count
    }
    float m0 = 0.f, m1 = 0.f, m2 = 0.f, m3 = 0.f, cc = 0.f;
    #pragma unroll 8
    for (int d = 0; d < DD; ++d) {
        float w2 = W2[d * DD + j];
        m0 = fmaf(W1[0 * DD + d], w2, m0);
        m1 = fmaf(W1[1 * DD + d], w2, m1);
        m2 = fmaf(W1[2 * DD + d], w2, m2);
        m3 = fmaf(W1[3 * DD + d], w2, m3);
        cc = fmaf(b1[d], w2, cc);
    }
    wsf[64 + 0 * DD + j] = m0;
    wsf[64 + 1 * DD + j] = m1;
    wsf[64 + 2 * DD + j] = m2;
    wsf[64 + 3 * DD + j] = m3;
    wsf[576 + j] = cc + b2[j];
}

// ---------------- K1: masked min/max of row/col + count ---------------------
__global__ __launch_bounds__(256) void k1_stats(const float* __restrict__ x0,
                                                int* __restrict__ wsi) {
    int tid = blockIdx.x * blockDim.x + threadIdx.x;
    int stride = gridDim.x * blockDim.x;
    int rmin = INT_MAX, rmax = -1, cmin = INT_MAX, cmax = -1, cnt = 0;
    const float4* x4 = (const float4*)x0;
    for (int i = tid; i < NPIX / 4; i += stride) {
        float4 v = x4[i];
        int base = i * 4;
        int r = base >> 10;          // 4 consecutive pixels never cross a row
        int c = base & (WW - 1);
        bool m0 = v.x != 0.0f, m1 = v.y != 0.0f, m2 = v.z != 0.0f, m3 = v.w != 0.0f;
        if (m0 | m1 | m2 | m3) {
            rmin = min(rmin, r);
            rmax = max(rmax, r);
            int clo = m0 ? c : (m1 ? c + 1 : (m2 ? c + 2 : c + 3));
            int chi = m3 ? c + 3 : (m2 ? c + 2 : (m1 ? c + 1 : c));
            cmin = min(cmin, clo);
            cmax = max(cmax, chi);
            cnt += (int)m0 + (int)m1 + (int)m2 + (int)m3;
        }
    }
    for (int off = 32; off >= 1; off >>= 1) {
        rmin = min(rmin, __shfl_down(rmin, off, 64));
        rmax = max(rmax, __shfl_down(rmax, off, 64));
        cmin = min(cmin, __shfl_down(cmin, off, 64));
        cmax = max(cmax, __shfl_down(cmax, off, 64));
        cnt += __shfl_down(cnt, off, 64);
    }
    __shared__ int s[4][5];
    int wave = threadIdx.x >> 6;
    int lane = threadIdx.x & 63;
    if (lane == 0) {
        s[wave][0] = rmin; s[wave][1] = rmax;
        s[wave][2] = cmin; s[wave][3] = cmax; s[wave][4] = cnt;
    }
    __syncthreads();
    if (threadIdx.x == 0) {
        int a0 = s[0][0], a1 = s[0][1], a2 = s[0][2], a3 = s[0][3], a4 = s[0][4];
        for (int w = 1; w < 4; ++w) {
            a0 = min(a0, s[w][0]); a1 = max(a1, s[w][1]);
            a2 = min(a2, s[w][2]); a3 = max(a3, s[w][3]); a4 += s[w][4];
        }
        atomicMin(&wsi[0], a0);
        atomicMax(&wsi[1], a1);
        atomicMin(&wsi[2], a2);
        atomicMax(&wsi[3], a3);
        atomicAdd(&wsi[4], a4);
    }
}

// ---------------- K2: main accumulate ---------------------------------------
// Tiles are 256-aligned and the image is 1024 wide -> a tile never crosses a
// row boundary: row is constant per tile, col is affine in p.
#define TILE 256
__global__ __launch_bounds__(256) void k2_main(const float* __restrict__ x0,
                                               const float* __restrict__ x1,
                                               const float* __restrict__ wsf,
                                               const int* __restrict__ wsi,
                                               float* __restrict__ partials,
                                               int C) {
    __shared__ float s0[TILE];
    __shared__ float s1[TILE];
    __shared__ float red[256];

    int tid = threadIdx.x;
    int j = tid & 127;   // feature
    int g = tid >> 7;    // pixel group 0/1

    int rmin = wsi[0], rmax = wsi[1], cmin = wsi[2], cmax = wsi[3];
    float rs = 1.0f / (float)(rmax - rmin);
    float cs = 1.0f / (float)(cmax - cmin);

    float M2 = wsf[64 + 2 * DD + j];
    float M3 = wsf[64 + 3 * DD + j];
    float a0 = wsf[64 + 0 * DD + j] * rs;
    float a1 = wsf[64 + 1 * DD + j] * cs;
    // fold the -min shifts into the constant
    float cp = wsf[576 + j] - (float)rmin * a0 - (float)cmin * a1;

    float acc = 0.0f;

    int start = blockIdx.x * C;
    int end = start + C;
    if (end > NPIX) end = NPIX;

    for (int tb = start; tb < end; tb += TILE) {
        int li = tb + tid;
        s0[tid] = (li < end) ? x0[li] : 0.0f;   // 0 -> masked out
        s1[tid] = (li < end) ? x1[li] : 0.0f;
        __syncthreads();

        float row = (float)(tb >> 10);
        float col0 = (float)((tb & (WW - 1)) + g * 128);
        // t = row*a0 + col*a1 + cp, advanced by += a1 per pixel
        float t = fmaf(row, a0, fmaf(col0, a1, cp));

        int pbase = g * 128;
        #pragma unroll 16
        for (int p = 0; p < 128; ++p) {
            float v0 = s0[pbase + p];   // uniform per wave -> LDS broadcast
            float v1 = s1[pbase + p];
            float dot = fmaf(v0, M2, fmaf(v1, M3, t));
            float r = fmaxf(dot, 0.0f);
            acc += (v0 != 0.0f) ? r : 0.0f;
            t += a1;
        }
        __syncthreads();
    }

    red[tid] = acc;
    __syncthreads();
    if (tid < 128) {
        partials[blockIdx.x * 128 + tid] = red[tid] + red[tid + 128];
    }
}

// ---------------- K3a: parallel reduce of partials -> m[j] ------------------
__global__ __launch_bounds__(256) void k3a_reduce(const float* __restrict__ partials,
                                                  const int* __restrict__ wsi,
                                                  float* __restrict__ m, int B) {
    int j = blockIdx.x;       // feature
    int tid = threadIdx.x;    // 256 threads over B partials
    float S = 0.0f;
    for (int b = tid; b < B; b += 256) S += partials[b * 128 + j];
    // wave reduce
    for (int off = 32; off >= 1; off >>= 1) S += __shfl_down(S, off, 64);
    __shared__ float s[4];
    int wave = tid >> 6, lane = tid & 63;
    if (lane == 0) s[wave] = S;
    __syncthreads();
    if (tid == 0) {
        float tot = s[0] + s[1] + s[2] + s[3];
        m[j] = tot / (float)wsi[4];
    }
}

// ---------------- K3b: final 128x128 matvec ---------------------------------
__global__ void k3b_matvec(const float* __restrict__ m, const float* __restrict__ W3,
                           const float* __restrict__ b3, float* __restrict__ out) {
    __shared__ float sm[128];
    int j = threadIdx.x;  // 128 threads
    sm[j] = m[j];
    __syncthreads();
    float acc = b3[j];
    #pragma unroll 16
    for (int d = 0; d < DD; ++d) acc = fmaf(sm[d], W3[d * DD + j], acc);
    out[j] = acc;
}

extern "C" void kernel_launch(void* const* d_in, const int* in_sizes, int n_in,
                              void* d_out, int out_size, void* d_ws, size_t ws_size,
                              hipStream_t stream) {
    const float* x  = (const float*)d_in[0];
    const float* x0 = x;
    const float* x1 = x + NPIX;
    const float* W1 = (const float*)d_in[1];
    const float* b1 = (const float*)d_in[2];
    const float* W2 = (const float*)d_in[3];
    const float* b2 = (const float*)d_in[4];
    const float* W3 = (const float*)d_in[5];
    const float* b3 = (const float*)d_in[6];
    float* out = (float*)d_out;

    float* wsf = (float*)d_ws;
    int*   wsi = (int*)d_ws;

    size_t avail = ws_size / 4;
    int B = 1024;
    if (avail < (size_t)(1024 + B * 128)) {
        B = (int)((avail > 1024 ? avail - 1024 : 128) / 128);
        if (B < 1) B = 1;
    }
    // round per-block chunk up to a multiple of TILE so tiles stay 256-aligned
    int C = (NPIX + B - 1) / B;
    C = (C + TILE - 1) / TILE * TILE;
    float* partials = wsf + 1024;
    float* m = wsf + 704;

    hipLaunchKernelGGL(k0_prep, dim3(1), dim3(128), 0, stream, W1, b1, W2, b2, wsf, wsi);
    hipLaunchKernelGGL(k1_stats, dim3(512), dim3(256), 0, stream, x0, wsi);
    hipLaunchKernelGGL(k2_main, dim3(B), dim3(256), 0, stream, x0, x1, wsf, wsi, partials, C);
    hipLaunchKernelGGL(k3a_reduce, dim3(128), dim3(256), 0, stream, partials, wsi, m, B);
    hipLaunchKernelGGL(k3b_matvec, dim3(1), dim3(128), 0, stream, m, W3, b3, out);
}

// Round 3
// 33.776 us; speedup vs baseline: 8.8802x; 2.1060x over previous
//
#include <hip/hip_runtime.h>
#include <climits>

#define HH 1024
#define WW 1024
#define DD 128
#define NPIX (HH * WW)
#define NSB 256   // stats blocks in kA
#define BB 1024   // kB blocks: one image row each

// ws 4B-unit layout:
//   wsf[64..576)    M (4x128 row-major)
//   wsf[576..704)   c (128)
//   wsi[1024..1280) rminP | [1280..1536) rmaxP | [1536..1792) cminP
//   wsi[1792..2048) cmaxP | [2048..2304) cntP
//   wsf[4096..4096+BB*128) partials

// ---------------- kA: per-block mask stats partials (SoA) + M,c prep --------
__global__ __launch_bounds__(256) void kA(const float* __restrict__ x0,
                                          const float* __restrict__ W1,
                                          const float* __restrict__ b1,
                                          const float* __restrict__ W2,
                                          const float* __restrict__ b2,
                                          float* __restrict__ wsf,
                                          int* __restrict__ wsi) {
    int blk = blockIdx.x;
    int tid = threadIdx.x;

    if (blk == NSB) {  // prep block: M = W1@W2, c = b1@W2 + b2
        if (tid < 128) {
            int j = tid;
            float m0 = 0.f, m1 = 0.f, m2 = 0.f, m3 = 0.f, cc = 0.f;
            #pragma unroll 16
            for (int d = 0; d < DD; ++d) {
                float w2 = W2[d * DD + j];
                m0 = fmaf(W1[0 * DD + d], w2, m0);
                m1 = fmaf(W1[1 * DD + d], w2, m1);
                m2 = fmaf(W1[2 * DD + d], w2, m2);
                m3 = fmaf(W1[3 * DD + d], w2, m3);
                cc = fmaf(b1[d], w2, cc);
            }
            wsf[64 + 0 * DD + j] = m0;
            wsf[64 + 1 * DD + j] = m1;
            wsf[64 + 2 * DD + j] = m2;
            wsf[64 + 3 * DD + j] = m3;
            wsf[576 + j] = cc + b2[j];
        }
        return;
    }

    // stats over float4 indices [blk*1024, blk*1024+1024)
    const float4* x4 = reinterpret_cast<const float4*>(x0);
    int base4 = blk * 1024;
    int rmin = INT_MAX, rmax = -1, cmin = INT_MAX, cmax = -1, cnt = 0;
    #pragma unroll
    for (int k = 0; k < 4; ++k) {
        int i = base4 + k * 256 + tid;
        float4 v = x4[i];
        int pix = i << 2;                 // 4 px of a float4 never cross a row
        int r = pix >> 10;
        int c = pix & (WW - 1);
        bool m0 = v.x != 0.f, m1 = v.y != 0.f, m2 = v.z != 0.f, m3 = v.w != 0.f;
        if (m0 | m1 | m2 | m3) {
            rmin = min(rmin, r);
            rmax = max(rmax, r);
            int clo = m0 ? c : (m1 ? c + 1 : (m2 ? c + 2 : c + 3));
            int chi = m3 ? c + 3 : (m2 ? c + 2 : (m1 ? c + 1 : c));
            cmin = min(cmin, clo);
            cmax = max(cmax, chi);
            cnt += (int)m0 + (int)m1 + (int)m2 + (int)m3;
        }
    }
    for (int off = 32; off >= 1; off >>= 1) {
        rmin = min(rmin, __shfl_xor(rmin, off, 64));
        rmax = max(rmax, __shfl_xor(rmax, off, 64));
        cmin = min(cmin, __shfl_xor(cmin, off, 64));
        cmax = max(cmax, __shfl_xor(cmax, off, 64));
        cnt += __shfl_xor(cnt, off, 64);
    }
    __shared__ int s[4][5];
    int wave = tid >> 6;
    if ((tid & 63) == 0) {
        s[wave][0] = rmin; s[wave][1] = rmax;
        s[wave][2] = cmin; s[wave][3] = cmax; s[wave][4] = cnt;
    }
    __syncthreads();
    if (tid == 0) {
        int a0 = s[0][0], a1 = s[0][1], a2 = s[0][2], a3 = s[0][3], a4 = s[0][4];
        for (int w = 1; w < 4; ++w) {
            a0 = min(a0, s[w][0]); a1 = max(a1, s[w][1]);
            a2 = min(a2, s[w][2]); a3 = max(a3, s[w][3]); a4 += s[w][4];
        }
        wsi[1024 + blk] = a0;
        wsi[1280 + blk] = a1;
        wsi[1536 + blk] = a2;
        wsi[1792 + blk] = a3;
        wsi[2048 + blk] = a4;
    }
}

// ---------------- kB: main accumulate, one image row per block --------------
__global__ __launch_bounds__(256) void kB(const float* __restrict__ x0,
                                          const float* __restrict__ x1,
                                          const float* __restrict__ wsf,
                                          const int* __restrict__ wsi,
                                          float* __restrict__ partials) {
    __shared__ float2 sv[1024];
    __shared__ float red[256];
    __shared__ int sred[4][4];
    __shared__ int lcnt;
    __shared__ int lidx[1024];

    int tid = threadIdx.x;
    int row = blockIdx.x;
    int j = tid & 127;   // feature
    int g = tid >> 7;    // pixel half 0/1

    // issue this row's pixel loads early
    const float4* x04 = reinterpret_cast<const float4*>(x0 + (size_t)row * WW);
    const float4* x14 = reinterpret_cast<const float4*>(x1 + (size_t)row * WW);
    float4 va = x04[tid];
    float4 vb = x14[tid];

    if (tid == 0) lcnt = 0;

    // reduce the 256 stats partials (SoA, one per thread)
    int rmin = wsi[1024 + tid];
    int rmax = wsi[1280 + tid];
    int cmin = wsi[1536 + tid];
    int cmax = wsi[1792 + tid];
    for (int off = 32; off >= 1; off >>= 1) {
        rmin = min(rmin, __shfl_xor(rmin, off, 64));
        rmax = max(rmax, __shfl_xor(rmax, off, 64));
        cmin = min(cmin, __shfl_xor(cmin, off, 64));
        cmax = max(cmax, __shfl_xor(cmax, off, 64));
    }
    int wave = tid >> 6;
    if ((tid & 63) == 0) {
        sred[wave][0] = rmin; sred[wave][1] = rmax;
        sred[wave][2] = cmin; sred[wave][3] = cmax;
    }
    __syncthreads();   // bar1: lcnt init + sred visible before atomics/reads

    // stage (v0,v1) interleaved; record exact-zero pixels (rare: usually none)
    float4* sv4 = reinterpret_cast<float4*>(sv);
    sv4[2 * tid]     = make_float4(va.x, vb.x, va.y, vb.y);
    sv4[2 * tid + 1] = make_float4(va.z, vb.z, va.w, vb.w);
    {
        float pv0 = va.x, pv1 = va.y, pv2 = va.z, pv3 = va.w;
        if ((__float_as_uint(pv0) << 1) == 0u) { int p = atomicAdd(&lcnt, 1); lidx[p] = 4 * tid + 0; }
        if ((__float_as_uint(pv1) << 1) == 0u) { int p = atomicAdd(&lcnt, 1); lidx[p] = 4 * tid + 1; }
        if ((__float_as_uint(pv2) << 1) == 0u) { int p = atomicAdd(&lcnt, 1); lidx[p] = 4 * tid + 2; }
        if ((__float_as_uint(pv3) << 1) == 0u) { int p = atomicAdd(&lcnt, 1); lidx[p] = 4 * tid + 3; }
    }
    __syncthreads();   // bar2: sv + lidx complete

    rmin = min(min(sred[0][0], sred[1][0]), min(sred[2][0], sred[3][0]));
    rmax = max(max(sred[0][1], sred[1][1]), max(sred[2][1], sred[3][1]));
    cmin = min(min(sred[0][2], sred[1][2]), min(sred[2][2], sred[3][2]));
    cmax = max(max(sred[0][3], sred[1][3]), max(sred[2][3], sred[3][3]));
    float rs = 1.0f / (float)(rmax - rmin);
    float cs = 1.0f / (float)(cmax - cmin);

    float M2 = wsf[64 + 2 * DD + j];
    float M3 = wsf[64 + 3 * DD + j];
    float a0 = wsf[64 + 0 * DD + j] * rs;
    float a1 = wsf[64 + 1 * DD + j] * cs;
    float cp = wsf[576 + j] - (float)rmin * a0 - (float)cmin * a1;

    // maskless main loop: 512 px per thread, 2 px per ds_read_b128 broadcast
    float t = fmaf((float)row, a0, fmaf((float)(g * 512), a1, cp));
    float a1x2 = a1 + a1;
    float acc0 = 0.f, acc1 = 0.f;
    const float4* base4 = reinterpret_cast<const float4*>(sv) + g * 256;
    #pragma unroll 8
    for (int q = 0; q < 256; ++q) {
        float4 v = base4[q];
        float d0 = fmaf(v.x, M2, fmaf(v.y, M3, t));
        float d1 = fmaf(v.z, M2, fmaf(v.w, M3, t + a1));
        acc0 += fmaxf(d0, 0.f);
        acc1 += fmaxf(d1, 0.f);
        t += a1x2;
    }
    float acc = acc0 + acc1;

    // subtract contributions of masked-out (zero) pixels
    int nz = lcnt;
    for (int ii = 0; ii < nz; ++ii) {
        int px = lidx[ii];
        if ((px >> 9) == g) {
            float2 v = sv[px];
            float tp = fmaf((float)row, a0, fmaf((float)px, a1, cp));
            acc -= fmaxf(fmaf(v.x, M2, fmaf(v.y, M3, tp)), 0.f);
        }
    }

    red[tid] = acc;
    __syncthreads();
    if (tid < 128) partials[(size_t)row * 128 + tid] = red[tid] + red[tid + 128];
}

// ---------------- kC: reduce partials + mean + final 128x128 matvec ---------
__global__ __launch_bounds__(1024) void kC(const float* __restrict__ partials,
                                           const int* __restrict__ wsi,
                                           const float* __restrict__ W3,
                                           const float* __restrict__ b3,
                                           float* __restrict__ out) {
    __shared__ float red[8][128];
    __shared__ float m[128];
    __shared__ int csum[4];

    int tid = threadIdx.x;
    int f = tid & 127;
    int ch = tid >> 7;   // 0..7

    // each thread sums 128 of the 1024 row-partials for feature f
    const float* p = partials + (size_t)ch * 128 * 128 + f;
    float S = 0.f;
    #pragma unroll 8
    for (int b = 0; b < 128; ++b) S += p[b * 128];
    red[ch][f] = S;

    // total mask count from the 256 SoA partials
    int cnt = 0;
    if (tid < 256) {
        cnt = wsi[2048 + tid];
        for (int off = 32; off >= 1; off >>= 1) cnt += __shfl_xor(cnt, off, 64);
        if ((tid & 63) == 0) csum[tid >> 6] = cnt;
    }
    __syncthreads();

    float cntf = (float)(csum[0] + csum[1] + csum[2] + csum[3]);
    if (tid < 128) {
        float tot = 0.f;
        #pragma unroll
        for (int w = 0; w < 8; ++w) tot += red[w][tid];
        m[tid] = tot / cntf;
    }
    __syncthreads();   // m ready; red phase-1 reads done -> safe to reuse red

    // matvec: thread (ch,f) covers d in [ch*16, ch*16+16)
    float acc = 0.f;
    #pragma unroll
    for (int k = 0; k < 16; ++k) {
        int d = ch * 16 + k;
        acc = fmaf(m[d], W3[d * DD + f], acc);
    }
    red[ch][f] = acc;
    __syncthreads();
    if (tid < 128) {
        float o = b3[tid];
        #pragma unroll
        for (int w = 0; w < 8; ++w) o += red[w][tid];
        out[tid] = o;
    }
}

extern "C" void kernel_launch(void* const* d_in, const int* in_sizes, int n_in,
                              void* d_out, int out_size, void* d_ws, size_t ws_size,
                              hipStream_t stream) {
    const float* x  = (const float*)d_in[0];
    const float* x0 = x;
    const float* x1 = x + NPIX;
    const float* W1 = (const float*)d_in[1];
    const float* b1 = (const float*)d_in[2];
    const float* W2 = (const float*)d_in[3];
    const float* b2 = (const float*)d_in[4];
    const float* W3 = (const float*)d_in[5];
    const float* b3 = (const float*)d_in[6];
    float* out = (float*)d_out;

    float* wsf = (float*)d_ws;
    int*   wsi = (int*)d_ws;
    float* partials = wsf + 4096;

    hipLaunchKernelGGL(kA, dim3(NSB + 1), dim3(256), 0, stream, x0, W1, b1, W2, b2, wsf, wsi);
    hipLaunchKernelGGL(kB, dim3(BB), dim3(256), 0, stream, x0, x1, wsf, wsi, partials);
    hipLaunchKernelGGL(kC, dim3(1), dim3(1024), 0, stream, partials, wsi, W3, b3, out);
}